// Round 7
// baseline (188.251 us; speedup 1.0000x reference)
//
#include <hip/hip_runtime.h>
#include <stdint.h>

#define HWPOS 1024
#define CCH   256
#define RROWS 128   // 2B
#define EPSF  1.1920928955078125e-07f

typedef __attribute__((ext_vector_type(8))) short   short8;
typedef __attribute__((ext_vector_type(4))) float   float4v;

__device__ __forceinline__ unsigned short f2bf(float f) {
  uint32_t x = __float_as_uint(f);
  x += 0x7FFFu + ((x >> 16) & 1u);          // RNE bf16
  return (unsigned short)(x >> 16);
}

// ws layout (16B-chunk units): addr16(hw,q,r,s8) = hw*4096 + q*1024 + r*8 + s8
//   q = c-quarter (64 channels = 8 chunks), r = row 0..127, s8 = swizzled
//   slot-in-quarter 0..7 (data chunk c8 stored at low3(c8)^(r&7) in its group).

// ---------------------------------------------------------------------------
// Kernel 1 (v5, LDS-tiled for DRAM granule size): block = 64 hw x 4 rows x
// 64 c (one c-quarter). Reads: 256 B segments (64 hw). Writes: 512 B
// contiguous (4 consecutive rows x 8 slots x 16 B by adjacent lanes).
// LDS chunk layout [rl][hwl][k]*16B with k = c8 ^ ((hwl>>3)&7) -> conflict-
// free b64 writes and b128 reads. ws layout identical to v4 (k_gram unchanged).
// ---------------------------------------------------------------------------
__global__ __launch_bounds__(256) void k_transpose(const float* __restrict__ inp,
                                                   const float* __restrict__ tgt,
                                                   unsigned short* __restrict__ wsF) {
  __shared__ unsigned short L[4 * 64 * 64];   // 32 KB
  const int t   = threadIdx.x;
  const int hwg = blockIdx.x;   // 0..15
  const int rg  = blockIdx.y;   // 0..31  (rows rg*4 .. rg*4+3; <16 inp, >=16 tgt)
  const int cqz = blockIdx.z;   // 0..3   c-quarter
  const int hw0 = hwg * 64;
  const int rbase = rg * 4;
  const float* src = (rg < 16) ? (inp + (size_t)(rg * 4) * CCH * HWPOS)
                               : (tgt + (size_t)((rg - 16) * 4) * CCH * HWPOS);
  // ---- phase A: global f32 -> regs -> bf16 -> LDS tile ----
  const int hw16 = t & 15;          // hw quad (4 hw)
  const int cs   = t >> 4;          // 0..15: c quad = cs*4
  const int cbase = cqz * 64 + cs * 4;
  float4 v[4][4];                   // [rl][cc]
#pragma unroll
  for (int rl = 0; rl < 4; ++rl)
#pragma unroll
    for (int cc = 0; cc < 4; ++cc)
      v[rl][cc] = *(const float4*)(src + ((size_t)rl * CCH + cbase + cc) * HWPOS
                                   + hw0 + hw16 * 4);
  const int c8l  = cs >> 1;         // chunk within quarter (0..7)
  const int half = (cs & 1) * 4;    // ushort offset within 16B chunk
#pragma unroll
  for (int rl = 0; rl < 4; ++rl) {
#pragma unroll
    for (int e = 0; e < 4; ++e) {
      const int hwl = hw16 * 4 + e;
      const int k   = c8l ^ ((hwl >> 3) & 7);
      float a = (e == 0) ? v[rl][0].x : (e == 1) ? v[rl][0].y : (e == 2) ? v[rl][0].z : v[rl][0].w;
      float b = (e == 0) ? v[rl][1].x : (e == 1) ? v[rl][1].y : (e == 2) ? v[rl][1].z : v[rl][1].w;
      float c = (e == 0) ? v[rl][2].x : (e == 1) ? v[rl][2].y : (e == 2) ? v[rl][2].z : v[rl][2].w;
      float d = (e == 0) ? v[rl][3].x : (e == 1) ? v[rl][3].y : (e == 2) ? v[rl][3].z : v[rl][3].w;
      uint2 o;
      o.x = f2bf(a) | ((uint32_t)f2bf(b) << 16);
      o.y = f2bf(c) | ((uint32_t)f2bf(d) << 16);
      *(uint2*)&L[((rl * 64 + hwl) * 8 + k) * 8 + half] = o;
    }
  }
  __syncthreads();
  // ---- phase B: LDS b128 -> global ws (512 B contiguous per 32 lanes) ----
  const int s8  = t & 7;
  const int rl2 = (t >> 3) & 3;
  const int hwp = t >> 5;           // 0..7
  const int rglob = rbase + rl2;
  const int c8w = s8 ^ (rglob & 7); // wanted data chunk for this slot
#pragma unroll
  for (int li = 0; li < 8; ++li) {
    const int hwl = li * 8 + hwp;
    const int k   = c8w ^ ((hwl >> 3) & 7);
    uint4 d = *(const uint4*)&L[((rl2 * 64 + hwl) * 8 + k) * 8];
    const size_t a16 = (size_t)(hw0 + hwl) * 4096 + (size_t)cqz * 1024 + rglob * 8 + s8;
    *(uint4*)(wsF + a16 * 8) = d;
  }
}

// ---------------------------------------------------------------------------
// Kernel 2 (v4, unchanged): one block per hw. Quarter-pipelined staging:
// 2 x 16KB LDS buffers; issue DMA for quarter q+1, compute quarter q, then
// barrier. 8 waves; wave w owns row-tile w x 8 col-tiles. No dynamic register
// indexing (scratch-free).
// ---------------------------------------------------------------------------
__global__ __launch_bounds__(512, 4) void k_gram(const unsigned short* __restrict__ wsF,
                                                 float* __restrict__ out) {
  __shared__ unsigned short Fs[2][8192];   // 2 x 16 KB quarter buffers
  __shared__ float sInv[RROWS];
  __shared__ float wred[8];
  const int t  = threadIdx.x;
  const int hw = blockIdx.x;
  const int lane = t & 63;
  const int w    = t >> 6;        // wave id 0..7 = row-tile
  const int lid  = lane & 15;
  const int quad = lane >> 4;
  const int lm   = lid & 7;       // r&7 for every row this lane touches
  float4v acc[8];
#pragma unroll
  for (int ni = 0; ni < 8; ++ni) acc[ni] = (float4v){0.f, 0.f, 0.f, 0.f};
  const unsigned short* gsrc = wsF + (size_t)hw * 65536;  // shorts per hw
#pragma unroll
  for (int it = 0; it < 2; ++it) {
    const size_t ch = (size_t)it * 512 + t;
    __builtin_amdgcn_global_load_lds(
        (const __attribute__((address_space(1))) unsigned int*)(gsrc + ch * 8),
        (__attribute__((address_space(3))) unsigned int*)(&Fs[0][0] + ch * 8),
        16, 0, 0);
  }
  __syncthreads();
#pragma unroll
  for (int q = 0; q < 4; ++q) {
    if (q < 3) {  // issue DMA for next quarter into other buffer (no wait)
#pragma unroll
      for (int it = 0; it < 2; ++it) {
        const size_t ch = (size_t)it * 512 + t;
        __builtin_amdgcn_global_load_lds(
            (const __attribute__((address_space(1))) unsigned int*)(gsrc + (size_t)(q + 1) * 16384 + ch * 8),
            (__attribute__((address_space(3))) unsigned int*)(&Fs[(q + 1) & 1][0] + ch * 8),
            16, 0, 0);
      }
    }
    const unsigned short* B = &Fs[q & 1][0];
#pragma unroll
    for (int ks2 = 0; ks2 < 2; ++ks2) {
      const int off = (((ks2 * 4 + quad) ^ lm) << 3);   // swizzled slot offset
      short8 a = *(const short8*)&B[((w << 4) | lid) * 64 + off];
#pragma unroll
      for (int ni = 0; ni < 8; ++ni) {
        short8 b = *(const short8*)&B[((ni << 4) | lid) * 64 + off];
        acc[ni] = __builtin_amdgcn_mfma_f32_16x16x32_bf16(a, b, acc[ni], 0, 0, 0);
      }
    }
    __syncthreads();   // drains next-quarter DMA (had full compute to finish)
  }
  // diagonal extract (no dynamic indexing): tile w (uniform), elem lid&3
  {
    float diagv = 0.f;
#pragma unroll
    for (int ni = 0; ni < 8; ++ni) {
      if (ni == w) {
#pragma unroll
        for (int e = 0; e < 4; ++e)
          if (e == (lid & 3)) diagv = acc[ni][e];
      }
    }
    if ((lid >> 2) == quad) {
      sInv[(w << 4) | lid] = 1.0f / fmaxf(sqrtf(diagv), EPSF);
    }
  }
  __syncthreads();
  float invj[8];
#pragma unroll
  for (int ni = 0; ni < 8; ++ni) invj[ni] = sInv[(ni << 4) | lid];
  const int tj = (w + 4) & 7;     // partner col-tile (wave-uniform)
  float lacc = 0.f;
#pragma unroll
  for (int reg = 0; reg < 4; ++reg) {
    const int rloc = quad * 4 + reg;           // local row in tile
    const int rg   = (w << 4) | rloc;          // global row 0..127
    const float invi = sInv[rg];
    float v[8];
#pragma unroll
    for (int ni = 0; ni < 8; ++ni) v[ni] = 2.0f * acc[ni][reg] * invi * invj[ni];
#pragma unroll
    for (int ni = 0; ni < 8; ++ni)
      if (ni == w && lid == rloc) v[ni] = -3.0e38f;   // mask diagonal
    float mx = v[0];
#pragma unroll
    for (int ni = 1; ni < 8; ++ni) mx = fmaxf(mx, v[ni]);
#pragma unroll
    for (int s = 1; s < 16; s <<= 1) mx = fmaxf(mx, __shfl_xor(mx, s, 16));
    float sm = 0.f;
#pragma unroll
    for (int ni = 0; ni < 8; ++ni) sm += __expf(v[ni] - mx);
#pragma unroll
    for (int s = 1; s < 16; s <<= 1) sm += __shfl_xor(sm, s, 16);
    const float lse = mx + __logf(sm);
    float cand = 0.f;
#pragma unroll
    for (int ni = 0; ni < 8; ++ni)
      if (ni == tj) cand = v[ni];                // positive-pair tile (uniform)
    const float vp = __shfl(cand, rloc, 16);
    lacc += vp - lse;                            // x16 lanes per row
  }
#pragma unroll
  for (int s = 1; s < 64; s <<= 1) lacc += __shfl_xor(lacc, s, 64);
  if (lane == 0) wred[w] = lacc;
  __syncthreads();
  if (t == 0) {
    float tot = 0.f;
#pragma unroll
    for (int i = 0; i < 8; ++i) tot += wred[i];
    // tot = 16 * sum_rows(pos) for this hw; loss = -sum/(HW*2B) with x16 dup
    atomicAdd(out, -tot * (1.0f / 2097152.0f));
  }
}

__global__ void k_zero(float* __restrict__ out) { out[0] = 0.0f; }

extern "C" void kernel_launch(void* const* d_in, const int* in_sizes, int n_in,
                              void* d_out, int out_size, void* d_ws, size_t ws_size,
                              hipStream_t stream) {
  const float* inp = (const float*)d_in[0];
  const float* tgt = (const float*)d_in[1];
  unsigned short* wsF = (unsigned short*)d_ws;
  k_zero<<<1, 1, 0, stream>>>((float*)d_out);
  k_transpose<<<dim3(16, 32, 4), 256, 0, stream>>>(inp, tgt, wsF);
  k_gram<<<dim3(HWPOS), 512, 0, stream>>>(wsF, (float*)d_out);
}

// Round 8
// 173.935 us; speedup vs baseline: 1.0823x; 1.0823x over previous
//
#include <hip/hip_runtime.h>
#include <stdint.h>

#define HWPOS 1024
#define CCH   256
#define RROWS 128   // 2B
#define EPSF  1.1920928955078125e-07f

typedef __attribute__((ext_vector_type(4))) float float4v;

__device__ __forceinline__ uint32_t pk4_fp8(float a, float b, float c, float d) {
  int v = 0;
  v = __builtin_amdgcn_cvt_pk_fp8_f32(a, b, v, false);  // bytes 0,1
  v = __builtin_amdgcn_cvt_pk_fp8_f32(c, d, v, true);   // bytes 2,3
  return (uint32_t)v;
}

// ws layout (fp8 bytes): addr(hw,r,s) = hw*32768 + r*256 + s*16  (+0..15)
//   s = swizzled 16B chunk slot: data chunk dd (c = dd*16..+15) stored at
//   slot s = dd ^ (r & 15)  -> conflict-free LDS b64 fragment reads in gram.

// ---------------------------------------------------------------------------
// Kernel 1 (v7, fp8): transpose [B,C,H,W] f32 -> ws fp8-e4m3 (layout above).
// Block = 2 rows x 32 hw x 256 c, LDS-free. Lane: 16 float4 loads (16 c at
// 1KB stride, 4 hw each); per wave-instruction: 8 FULL 128B read granules.
// Stores: per (hw,q) 8 lanes write 8 swizzle-permuted 16B chunks covering an
// aligned 128B half-row -> full write granules. Also zeroes out[0] (block 0).
// ---------------------------------------------------------------------------
__global__ __launch_bounds__(256) void k_transpose(const float* __restrict__ inp,
                                                   const float* __restrict__ tgt,
                                                   unsigned char* __restrict__ wsF,
                                                   float* __restrict__ out) {
  const int t    = threadIdx.x;
  const int hq   = t & 7;           // hw quad (4 hw)
  const int dd   = (t >> 3) & 15;   // c-chunk (16 c)
  const int rsel = t >> 7;          // 0..1
  const int r    = blockIdx.y * 2 + rsel;
  const int hw0  = blockIdx.x * 32;
  if (blockIdx.x == 0 && blockIdx.y == 0 && t == 0) out[0] = 0.0f;
  const int m = r & 15;
  const int s = dd ^ m;             // swizzled chunk slot
  const float* src = (r < 64) ? (inp + (size_t)r * CCH * HWPOS)
                              : (tgt + (size_t)(r - 64) * CCH * HWPOS);
  const float* p = src + (size_t)(dd * 16) * HWPOS + hw0 + hq * 4;
  float4 v[16];
#pragma unroll
  for (int e = 0; e < 16; ++e) v[e] = *(const float4*)(p + (size_t)e * HWPOS);
#pragma unroll
  for (int q = 0; q < 4; ++q) {
    float x[16];
#pragma unroll
    for (int e = 0; e < 16; ++e)
      x[e] = (q == 0) ? v[e].x : (q == 1) ? v[e].y : (q == 2) ? v[e].z : v[e].w;
    uint4 o;
    o.x = pk4_fp8(x[0],  x[1],  x[2],  x[3]);
    o.y = pk4_fp8(x[4],  x[5],  x[6],  x[7]);
    o.z = pk4_fp8(x[8],  x[9],  x[10], x[11]);
    o.w = pk4_fp8(x[12], x[13], x[14], x[15]);
    const size_t a = (size_t)(hw0 + hq * 4 + q) * 32768 + (size_t)r * 256 + s * 16;
    *(uint4*)(wsF + a) = o;
  }
}

// ---------------------------------------------------------------------------
// Kernel 2 (v5, fp8): one block per hw. Whole 32KB fp8 image in ONE LDS
// buffer (single barrier, no K-split pipeline). 8 waves; wave w owns row-tile
// w x 8 col-tiles via mfma_f32_16x16x32_fp8_fp8 (b64 frags). Norms from the
// gram diagonal; fused masked log-softmax + positive-pair extraction; one
// atomicAdd per block. Scratch-free (no dynamic register indexing).
// ---------------------------------------------------------------------------
__global__ __launch_bounds__(512, 4) void k_gram(const unsigned char* __restrict__ wsF,
                                                 float* __restrict__ out) {
  __shared__ unsigned char Fs[32768];   // full fp8 image, swizzled
  __shared__ float sInv[RROWS];
  __shared__ float wred[8];
  const int t  = threadIdx.x;
  const int hw = blockIdx.x;
  const int lane = t & 63;
  const int w    = t >> 6;        // wave id 0..7 = row-tile
  const int lid  = lane & 15;
  const int quad = lane >> 4;
  float4v acc[8];
#pragma unroll
  for (int ni = 0; ni < 8; ++ni) acc[ni] = (float4v){0.f, 0.f, 0.f, 0.f};
  const unsigned char* gsrc = wsF + (size_t)hw * 32768;
#pragma unroll
  for (int it = 0; it < 4; ++it) {
    const size_t ch = (size_t)it * 512 + t;
    __builtin_amdgcn_global_load_lds(
        (const __attribute__((address_space(1))) unsigned int*)(gsrc + ch * 16),
        (__attribute__((address_space(3))) unsigned int*)(Fs + ch * 16),
        16, 0, 0);
  }
  __syncthreads();
  const int rowA = (w << 4) | lid;
#pragma unroll
  for (int ks = 0; ks < 8; ++ks) {
    const int d    = 2 * ks + (quad >> 1);      // data chunk for this frag
    const int off  = ((d ^ lid) << 4) + (quad & 1) * 8;  // swizzled byte off
    long a = *(const long*)&Fs[rowA * 256 + off];
#pragma unroll
    for (int ni = 0; ni < 8; ++ni) {
      long b = *(const long*)&Fs[(((ni << 4) | lid)) * 256 + off];
      acc[ni] = __builtin_amdgcn_mfma_f32_16x16x32_fp8_fp8(a, b, acc[ni], 0, 0, 0);
    }
  }
  // diagonal extract (no dynamic indexing): tile w (uniform), elem lid&3
  {
    float diagv = 0.f;
#pragma unroll
    for (int ni = 0; ni < 8; ++ni) {
      if (ni == w) {
#pragma unroll
        for (int e = 0; e < 4; ++e)
          if (e == (lid & 3)) diagv = acc[ni][e];
      }
    }
    if ((lid >> 2) == quad) {
      sInv[(w << 4) | lid] = 1.0f / fmaxf(sqrtf(diagv), EPSF);
    }
  }
  __syncthreads();
  float invj[8];
#pragma unroll
  for (int ni = 0; ni < 8; ++ni) invj[ni] = sInv[(ni << 4) | lid];
  const int tj = (w + 4) & 7;     // partner col-tile (wave-uniform)
  float lacc = 0.f;
#pragma unroll
  for (int reg = 0; reg < 4; ++reg) {
    const int rloc = quad * 4 + reg;           // local row in tile
    const int rg   = (w << 4) | rloc;          // global row 0..127
    const float invi = sInv[rg];
    float v[8];
#pragma unroll
    for (int ni = 0; ni < 8; ++ni) v[ni] = 2.0f * acc[ni][reg] * invi * invj[ni];
#pragma unroll
    for (int ni = 0; ni < 8; ++ni)
      if (ni == w && lid == rloc) v[ni] = -3.0e38f;   // mask diagonal
    float mx = v[0];
#pragma unroll
    for (int ni = 1; ni < 8; ++ni) mx = fmaxf(mx, v[ni]);
#pragma unroll
    for (int sh = 1; sh < 16; sh <<= 1) mx = fmaxf(mx, __shfl_xor(mx, sh, 16));
    float sm = 0.f;
#pragma unroll
    for (int ni = 0; ni < 8; ++ni) sm += __expf(v[ni] - mx);
#pragma unroll
    for (int sh = 1; sh < 16; sh <<= 1) sm += __shfl_xor(sm, sh, 16);
    const float lse = mx + __logf(sm);
    float cand = 0.f;
#pragma unroll
    for (int ni = 0; ni < 8; ++ni)
      if (ni == tj) cand = v[ni];                // positive-pair tile (uniform)
    const float vp = __shfl(cand, rloc, 16);
    lacc += vp - lse;                            // x16 lanes per row
  }
#pragma unroll
  for (int sh = 1; sh < 64; sh <<= 1) lacc += __shfl_xor(lacc, sh, 64);
  if (lane == 0) wred[w] = lacc;
  __syncthreads();
  if (t == 0) {
    float tot = 0.f;
#pragma unroll
    for (int i = 0; i < 8; ++i) tot += wred[i];
    // tot = 16 * sum_rows(pos) for this hw; loss = -sum/(HW*2B) with x16 dup
    atomicAdd(out, -tot * (1.0f / 2097152.0f));
  }
}

extern "C" void kernel_launch(void* const* d_in, const int* in_sizes, int n_in,
                              void* d_out, int out_size, void* d_ws, size_t ws_size,
                              hipStream_t stream) {
  const float* inp = (const float*)d_in[0];
  const float* tgt = (const float*)d_in[1];
  unsigned char* wsF = (unsigned char*)d_ws;
  k_transpose<<<dim3(32, 64), 256, 0, stream>>>(inp, tgt, wsF, (float*)d_out);
  k_gram<<<dim3(HWPOS), 512, 0, stream>>>(wsF, (float*)d_out);
}